// Round 1
// baseline (198.136 us; speedup 1.0000x reference)
//
#include <hip/hip_runtime.h>
#include <hip/hip_bf16.h>

// Problem: B=32, S=2048, D=512, FULL=60000.
// vals[b,s] = dot(h[b,s,:], w) + bias;  out[b, gene_pos[b,s]] = vals  (pos<FULL)
// Memory-bound: 134 MB read of h dominates (roofline ~21 us @ 6.3 TB/s).
//
// V2: 8 tokens per wave.
//  - w hoisted into registers once per wave (was: re-loaded by all 65536 waves
//    = 134 MB of redundant L1 traffic, 2x load-issue count).
//  - all 16 h dwordx4 loads issued before first use -> 16 outstanding loads/wave.
//  - grouped reduction: 3 common butterfly steps per token (xor 32/16/8), then
//    each 8-lane group takes one token and finishes with xor 4/2/1.
//    27 shfls per 8 tokens instead of 48.
//  - gene_pos read as one coalesced 32B segment by lanes 0,8,...,56.

#define B_DIM 32
#define S_DIM 2048
#define D_DIM 512
#define FULL_LEN 60000
#define TOK_PER_WAVE 8

__global__ __launch_bounds__(256) void conv_scatter_kernel(
        const float* __restrict__ h,
        const int* __restrict__ gene_pos,
        const float* __restrict__ w,
        const float* __restrict__ bias,
        float* __restrict__ out) {
    const int wave = threadIdx.x >> 6;                       // 0..3
    const int lane = threadIdx.x & 63;
    const int base = (((blockIdx.x << 2) + wave) << 3);      // first token of this wave
    // grid sized exactly: 65536 tokens / (4 waves * 8 tok) = 2048 blocks

    const int v = lane << 1;                                 // float4 index: lane covers [8*lane, 8*lane+8)
    const float4* wp = (const float4*)w;
    const float4 w0 = wp[v];
    const float4 w1 = wp[v + 1];

    const float4* hp = (const float4*)(h + (size_t)base * D_DIM);

    float s[TOK_PER_WAVE];
    #pragma unroll
    for (int t = 0; t < TOK_PER_WAVE; ++t) {
        const float4 a0 = hp[t * (D_DIM / 4) + v];
        const float4 a1 = hp[t * (D_DIM / 4) + v + 1];
        s[t] = a0.x * w0.x + a0.y * w0.y + a0.z * w0.z + a0.w * w0.w
             + a1.x * w1.x + a1.y * w1.y + a1.z * w1.z + a1.w * w1.w;
    }

    // Common butterfly steps: after xor 32,16,8 each lane holds, for token t,
    // the partial sum over the 8 lanes {m : m&7 == lane&7}.
    #pragma unroll
    for (int t = 0; t < TOK_PER_WAVE; ++t) {
        s[t] += __shfl_xor(s[t], 32, 64);
        s[t] += __shfl_xor(s[t], 16, 64);
        s[t] += __shfl_xor(s[t], 8, 64);
    }

    // 8-lane group g finishes token (base+g): select s[g], butterfly xor 4,2,1.
    const int g = lane >> 3;
    float r = s[0];
    #pragma unroll
    for (int t = 1; t < TOK_PER_WAVE; ++t)
        r = (g == t) ? s[t] : r;
    r += __shfl_xor(r, 4, 64);
    r += __shfl_xor(r, 2, 64);
    r += __shfl_xor(r, 1, 64);
    // every lane of group g now holds the full 64-lane dot for token base+g

    if ((lane & 7) == 0) {
        const int token = base + g;                          // lanes 0,8..56 -> tokens base..base+7
        const int pos = gene_pos[token];                     // one 32B coalesced segment
        if (pos < FULL_LEN) {
            const int brow = token >> 11;                    // token / S_DIM
            out[(size_t)brow * FULL_LEN + pos] = r + bias[0];
        }
    }
}

extern "C" void kernel_launch(void* const* d_in, const int* in_sizes, int n_in,
                              void* d_out, int out_size, void* d_ws, size_t ws_size,
                              hipStream_t stream) {
    const float* h        = (const float*)d_in[0];
    const int*   gene_pos = (const int*)d_in[1];
    const float* w        = (const float*)d_in[2];
    const float* bias     = (const float*)d_in[3];
    float* out = (float*)d_out;

    // d_out is re-poisoned to 0xAA before every timed launch: zero it.
    hipMemsetAsync(out, 0, (size_t)out_size * sizeof(float), stream);

    const int tokens = B_DIM * S_DIM;                        // 65536
    const int blocks = tokens / (4 * TOK_PER_WAVE);          // 2048
    conv_scatter_kernel<<<blocks, 256, 0, stream>>>(h, gene_pos, w, bias, out);
}